// Round 14
// baseline (163.098 us; speedup 1.0000x reference)
//
#include <hip/hip_runtime.h>
#include <math.h>

// LocalContrastNormalization: out = sigmoid(0.5*(x-mu)/(sigma+eps)),
// mu/sigma from 31x31 zero-padded box filter (separable).
// v13b = v13 with the nontemporal-store compile fix (native ext_vector
// type instead of HIP_vector_type). Changes vs v10:
//  1) SH=128 -> grid 256 -> 1 block/CU: the 31-row slide-reuse window
//     (124 KB/CU, 4 MB/XCD) now fits L2, so sub-row and x-row re-reads
//     become L2 hits instead of HBM fetches. XCD swizzle keeps adjacent
//     chunks of an image on one XCD so the 30-row halo is L2-shared too.
//  2) NON-TEMPORAL output stores: output lines are never re-read; nt stops
//     131 MB of write-allocate from evicting the read-reuse window.

#define KSZ    31
#define PAD    15
#define IMG_H  1024
#define IMG_W  1024
#define SH     128               // rows per block
#define GP     4                 // rows per group/phase
#define NPH    (SH / GP)         // 32 phases
#define NT     512
#define LROW   66                // transposed stride in float2 units
#define LBUF   (16 * LROW)       // 1056 float2 per row-slot
#define EPSV   1e-5f

typedef float nfloat4 __attribute__((ext_vector_type(4)));

#define LDS_BARRIER() do {                                   \
    asm volatile("s_waitcnt lgkmcnt(0)" ::: "memory");       \
    __builtin_amdgcn_s_barrier();                            \
} while (0)

__global__ __launch_bounds__(NT, 4)
void lcn_fused_kernel(const float* __restrict__ x, float* __restrict__ out) {
    // XCD-aware bijective swizzle (gridDim.x = 256, %8==0): the 8 chunks of
    // one image land on one XCD -> inter-chunk halo rows are L2-shared.
    const int cpx = gridDim.x >> 3;
    const int bid = (blockIdx.x & 7) * cpx + (blockIdx.x >> 3);

    const int chunk = bid & 7;             // 8 chunks of 128 rows per image
    const int b     = bid >> 3;
    const int y0    = chunk * SH;

    const float* img  = x   + (size_t)b * (IMG_H * IMG_W);
    float*       oimg = out + (size_t)b * (IMG_H * IMG_W);

    __shared__ float2 vbuf[2][GP][LBUF];   // double-buffered, transposed

    const int t    = threadIdx.x;
    const int wave = t >> 6;               // 0..7
    const int lane = t & 63;

    // Pad init: left pads (iv<16) and right pads must be zero.
    if (t < 256) {
        const int s = t >> 5;              // slot 0..7
        const int k = t & 31;
        float2* vb = &vbuf[s >> 2][s & 3][0];
        if (k < 16) vb[k * LROW] = make_float2(0.f, 0.f);
        else        vb[(k - 16) * LROW + (LROW - 1)] = make_float2(0.f, 0.f);
    }

    const float inv = 1.0f / 961.0f;

    if (wave >= 4) {
        // ================= PRODUCER (waves 4..7) =================
        const int pt = t & 255;            // 0..255
        const int c0 = 4 * pt;             // 4 consecutive cols

        const int iv  = c0 + 16;
        const int wp0 = ((iv    ) & 15) * LROW + ((iv    ) >> 4);
        const int wp1 = ((iv + 1) & 15) * LROW + ((iv + 1) >> 4);
        const int wp2 = ((iv + 2) & 15) * LROW + ((iv + 2) >> 4);
        const int wp3 = ((iv + 3) & 15) * LROW + ((iv + 3) >> 4);

        // Warm-up: W(y0) over rows [y0-15, y0+15] (top never clips: y0<=896).
        float vs0=0,vs1=0,vs2=0,vs3=0, vq0=0,vq1=0,vq2=0,vq3=0;
        for (int y = y0 - PAD; y <= y0 + PAD; ++y) {
            const int yc = max(y, 0);
            float4 v = *(const float4*)(img + (size_t)yc * IMG_W + c0);
            const float m = (y >= 0) ? 1.f : 0.f;
            v.x *= m; v.y *= m; v.z *= m; v.w *= m;
            vs0 += v.x; vq0 = fmaf(v.x, v.x, vq0);
            vs1 += v.y; vq1 = fmaf(v.y, v.y, vq1);
            vs2 += v.z; vq2 = fmaf(v.z, v.z, vq2);
            vs3 += v.w; vq3 = fmaf(v.w, v.w, vq3);
        }

        // Prologue: publish G0 (rows y0..y0+3) into buf0, sliding directly.
        #pragma unroll
        for (int r = 0; r < GP; ++r) {
            vbuf[0][r][wp0] = make_float2(vs0, vq0);
            vbuf[0][r][wp1] = make_float2(vs1, vq1);
            vbuf[0][r][wp2] = make_float2(vs2, vq2);
            vbuf[0][r][wp3] = make_float2(vs3, vq3);
            const int ys  = y0 + r - PAD;
            const int ya  = y0 + r + PAD + 1;      // <= y0+19: never clips
            const int ysc = max(ys, 0);
            float4 vS = *(const float4*)(img + (size_t)ysc * IMG_W + c0);
            float4 vA = *(const float4*)(img + (size_t)ya  * IMG_W + c0);
            const float mS = (ys >= 0) ? 1.f : 0.f;
            float s0 = vS.x*mS, s1 = vS.y*mS, s2 = vS.z*mS, s3 = vS.w*mS;
            vs0 += vA.x - s0; vq0 = fmaf(vA.x, vA.x, vq0); vq0 = fmaf(-s0, s0, vq0);
            vs1 += vA.y - s1; vq1 = fmaf(vA.y, vA.y, vq1); vq1 = fmaf(-s1, s1, vq1);
            vs2 += vA.z - s2; vq2 = fmaf(vA.z, vA.z, vq2); vq2 = fmaf(-s2, s2, vq2);
            vs3 += vA.w - s3; vq3 = fmaf(vA.w, vA.w, vq3); vq3 = fmaf(-s3, s3, vq3);
        }

        // Prefetch slide rows for phase 0's publish (base y0+GP).
        float4 pfS[GP], pfA[GP];
        {
            const int base = y0 + GP;
            #pragma unroll
            for (int r = 0; r < GP; ++r) {
                const int ys = base + r - PAD;
                const int ya = base + r + PAD + 1;
                pfS[r] = *(const float4*)(img + (size_t)max(ys, 0) * IMG_W + c0);
                pfA[r] = *(const float4*)(img + (size_t)min(ya, IMG_H - 1) * IMG_W + c0);
            }
        }

        for (int p = 0; p < NPH; ++p) {
            LDS_BARRIER();
            if (p < NPH - 1) {
                const int base = y0 + GP * (p + 1);
                float2* dst = &vbuf[(p + 1) & 1][0][0];
                #pragma unroll
                for (int r = 0; r < GP; ++r) {
                    float2* d = dst + r * LBUF;
                    d[wp0] = make_float2(vs0, vq0);
                    d[wp1] = make_float2(vs1, vq1);
                    d[wp2] = make_float2(vs2, vq2);
                    d[wp3] = make_float2(vs3, vq3);
                    const int ys = base + r - PAD;
                    const int ya = base + r + PAD + 1;
                    const float mS = (ys >= 0)    ? 1.f : 0.f;
                    const float mA = (ya < IMG_H) ? 1.f : 0.f;
                    float s0 = pfS[r].x*mS, s1 = pfS[r].y*mS,
                          s2 = pfS[r].z*mS, s3 = pfS[r].w*mS;
                    float a0 = pfA[r].x*mA, a1 = pfA[r].y*mA,
                          a2 = pfA[r].z*mA, a3 = pfA[r].w*mA;
                    vs0 += a0 - s0; vq0 = fmaf(a0, a0, vq0); vq0 = fmaf(-s0, s0, vq0);
                    vs1 += a1 - s1; vq1 = fmaf(a1, a1, vq1); vq1 = fmaf(-s1, s1, vq1);
                    vs2 += a2 - s2; vq2 = fmaf(a2, a2, vq2); vq2 = fmaf(-s2, s2, vq2);
                    vs3 += a3 - s3; vq3 = fmaf(a3, a3, vq3); vq3 = fmaf(-s3, s3, vq3);
                }
                if (p < NPH - 2) {        // prefetch for next phase's publish
                    const int base2 = y0 + GP * (p + 2);
                    #pragma unroll
                    for (int r = 0; r < GP; ++r) {
                        const int ys = base2 + r - PAD;
                        const int ya = base2 + r + PAD + 1;
                        pfS[r] = *(const float4*)(img + (size_t)max(ys, 0) * IMG_W + c0);
                        pfA[r] = *(const float4*)(img + (size_t)min(ya, IMG_H - 1) * IMG_W + c0);
                    }
                }
            }
        }
    } else {
        // ================= CONSUMER (waves 0..3) =================
        const int cbase = lane << 4;       // 16 contiguous cols per lane

        for (int p = 0; p < NPH; ++p) {
            LDS_BARRIER();
            const int row = y0 + GP * p + wave;

            // x-row issued first; latency hidden under the LDS warm-up.
            // (Normal load: should L2-hit against the producer add-read of
            // this row 4 phases earlier.)
            const float* xr = img + (size_t)row * IMG_W + cbase;
            float4 xa = ((const float4*)xr)[0];
            float4 xb = ((const float4*)xr)[1];
            float4 xc = ((const float4*)xr)[2];
            float4 xd = ((const float4*)xr)[3];

            const float2* vr = &vbuf[p & 1][wave][lane];

            // Warm-up with 2-way ILP split.
            float hsA = 0.f, hqA = 0.f, hsB = 0.f, hqB = 0.f;
            #pragma unroll
            for (int s = 1; s <= 31; s += 2) {
                float2 va = vr[(s & 15) * LROW + (s >> 4)];
                hsA += va.x; hqA += va.y;
                if (s + 1 <= 31) {
                    float2 vb2 = vr[((s + 1) & 15) * LROW + ((s + 1) >> 4)];
                    hsB += vb2.x; hqB += vb2.y;
                }
            }
            float hs = hsA + hsB, hq = hqA + hqB;

            float xs[16] = { xa.x, xa.y, xa.z, xa.w,  xb.x, xb.y, xb.z, xb.w,
                             xc.x, xc.y, xc.z, xc.w,  xd.x, xd.y, xd.z, xd.w };
            float res[16];
            #pragma unroll
            for (int j = 0; j < 16; ++j) {
                if (j > 0) {
                    float2 va  = vr[((j - 1) & 15) * LROW + 2];   // iv=cbase+j+31
                    float2 vsu = vr[(j & 15) * LROW];             // iv=cbase+j
                    hs += va.x - vsu.x;
                    hq += va.y - vsu.y;
                }
                const float mean = hs * inv;
                const float var  = fmaf(-mean, mean, hq * inv);
                const float stdv = sqrtf(fmaxf(var, EPSV));
                const float norm = (xs[j] - mean) *
                                   __builtin_amdgcn_rcpf(stdv + EPSV);
                res[j] = __builtin_amdgcn_rcpf(1.0f + __expf(-0.5f * norm));
            }

            // NON-TEMPORAL stores via native ext_vector type (compile fix).
            // Pattern still the proven full-4KB-per-wave, 64B-per-lane epilogue.
            nfloat4* orow = (nfloat4*)(oimg + (size_t)row * IMG_W + cbase);
            nfloat4 r0; r0.x = res[0];  r0.y = res[1];  r0.z = res[2];  r0.w = res[3];
            nfloat4 r1; r1.x = res[4];  r1.y = res[5];  r1.z = res[6];  r1.w = res[7];
            nfloat4 r2; r2.x = res[8];  r2.y = res[9];  r2.z = res[10]; r2.w = res[11];
            nfloat4 r3; r3.x = res[12]; r3.y = res[13]; r3.z = res[14]; r3.w = res[15];
            __builtin_nontemporal_store(r0, orow);
            __builtin_nontemporal_store(r1, orow + 1);
            __builtin_nontemporal_store(r2, orow + 2);
            __builtin_nontemporal_store(r3, orow + 3);
        }
    }
}

extern "C" void kernel_launch(void* const* d_in, const int* in_sizes, int n_in,
                              void* d_out, int out_size, void* d_ws, size_t ws_size,
                              hipStream_t stream) {
    (void)n_in; (void)out_size; (void)d_ws; (void)ws_size;
    const float* x = (const float*)d_in[0];
    float* out = (float*)d_out;
    const int B = in_sizes[0] / (IMG_H * IMG_W);   // 32
    dim3 grid(B * (IMG_H / SH));                   // 256 blocks, 1 per CU
    lcn_fused_kernel<<<grid, NT, 0, stream>>>(x, out);
}

// Round 15
// 96.873 us; speedup vs baseline: 1.6836x; 1.6836x over previous
//
#include <hip/hip_runtime.h>
#include <math.h>

// LocalContrastNormalization: out = sigmoid(0.5*(x-mu)/(sigma+eps)),
// mu/sigma from 31x31 zero-padded box filter (separable).
// v15: v10's producer/consumer structure at FULL OCCUPANCY (32 waves/CU).
//  - NT=1024: waves 0..7 consumers (1 full row each per phase, 16 cols/lane,
//    proven 64B/lane normal-store epilogue), waves 8..15 producers (2
//    cols/thread vertical sliding sums, phase-ahead prefetched slides).
//  - GP=8 rows/phase, SINGLE-buffered 8-slot transposed LDS (67.6 KB) ->
//    2 blocks/CU x 16 waves = 32 waves/CU (vs v10's 16).
//  - Two lgkm-only barriers per phase (publish-visible / reads-done), same
//    0.25 barriers/row as v10; producer loads stay in flight across both.
//  - No nt-stores (R14: +139MB write amp), no SH=128 (R14: occupancy loss),
//    full-width rows (R5/R12: half-width stores amplify).

#define KSZ    31
#define PAD    15
#define IMG_H  1024
#define IMG_W  1024
#define SH     64                // rows per block
#define GP     8                 // rows per phase == consumer waves
#define NPH    (SH / GP)         // 8 phases
#define NT     1024
#define NCONS  512               // threads 0..511 = consumer waves 0..7
#define LROW   66                // transposed stride in float2 units
#define LBUF   (16 * LROW)       // 1056 float2 per row-slot
#define EPSV   1e-5f

#define LDS_BARRIER() do {                                   \
    asm volatile("s_waitcnt lgkmcnt(0)" ::: "memory");       \
    __builtin_amdgcn_s_barrier();                            \
} while (0)

__global__ __launch_bounds__(NT, 8)
void lcn_fused_kernel(const float* __restrict__ x, float* __restrict__ out) {
    // XCD-aware bijective swizzle (gridDim.x = 512, %8==0).
    const int cpx = gridDim.x >> 3;
    const int bid = (blockIdx.x & 7) * cpx + (blockIdx.x >> 3);

    const int chunk = bid & 15;            // 16 chunks of 64 rows per image
    const int b     = bid >> 4;
    const int y0    = chunk * SH;

    const float* img  = x   + (size_t)b * (IMG_H * IMG_W);
    float*       oimg = out + (size_t)b * (IMG_H * IMG_W);

    __shared__ float2 vbuf[GP][LBUF];      // single-buffered, transposed

    const int t    = threadIdx.x;
    const int wave = t >> 6;               // 0..15
    const int lane = t & 63;

    const float inv = 1.0f / 961.0f;

    if (t >= NCONS) {
        // ================= PRODUCER (waves 8..15) =================
        const int pt = t - NCONS;          // 0..511
        const int c0 = 2 * pt;             // 2 consecutive cols

        const int iv  = c0 + 16;
        const int wp0 = ((iv    ) & 15) * LROW + ((iv    ) >> 4);
        const int wp1 = ((iv + 1) & 15) * LROW + ((iv + 1) >> 4);

        // Warm-up: W(y0) over rows [y0-15, y0+15] (top never clips: y0<=960).
        float vs0 = 0.f, vq0 = 0.f, vs1 = 0.f, vq1 = 0.f;
        for (int y = y0 - PAD; y <= y0 + PAD; ++y) {
            const int yc = max(y, 0);
            float2 v = *(const float2*)(img + (size_t)yc * IMG_W + c0);
            const float m = (y >= 0) ? 1.f : 0.f;
            v.x *= m; v.y *= m;
            vs0 += v.x; vq0 = fmaf(v.x, v.x, vq0);
            vs1 += v.y; vq1 = fmaf(v.y, v.y, vq1);
        }

        // Prologue: publish G0 (rows y0..y0+7), sliding with direct loads.
        #pragma unroll
        for (int r = 0; r < GP; ++r) {
            vbuf[r][wp0] = make_float2(vs0, vq0);
            vbuf[r][wp1] = make_float2(vs1, vq1);
            const int ys  = y0 + r - PAD;
            const int ya  = y0 + r + PAD + 1;      // <= y0+23 <= 983: no clip
            const int ysc = max(ys, 0);
            float2 vS = *(const float2*)(img + (size_t)ysc * IMG_W + c0);
            float2 vA = *(const float2*)(img + (size_t)ya  * IMG_W + c0);
            const float mS = (ys >= 0) ? 1.f : 0.f;
            float s0 = vS.x * mS, s1 = vS.y * mS;
            vs0 += vA.x - s0; vq0 = fmaf(vA.x, vA.x, vq0); vq0 = fmaf(-s0, s0, vq0);
            vs1 += vA.y - s1; vq1 = fmaf(vA.y, vA.y, vq1); vq1 = fmaf(-s1, s1, vq1);
        }

        // Prefetch slide loads for G1 (publish base y0+GP).
        float2 sbv[GP], adv[GP];
        {
            const int base = y0 + GP;
            #pragma unroll
            for (int r = 0; r < GP; ++r) {
                const int ys = base + r - PAD;
                const int ya = base + r + PAD + 1;
                sbv[r] = *(const float2*)(img + (size_t)max(ys, 0) * IMG_W + c0);
                adv[r] = *(const float2*)(img + (size_t)min(ya, IMG_H - 1) * IMG_W + c0);
            }
        }

        for (int p = 0; p < NPH; ++p) {
            LDS_BARRIER();                 // B: G_p visible (consumers read)
            LDS_BARRIER();                 // A: consumers' reads of G_p done
            if (p < NPH - 1) {
                const int base = y0 + GP * (p + 1);
                #pragma unroll
                for (int r = 0; r < GP; ++r) {
                    vbuf[r][wp0] = make_float2(vs0, vq0);
                    vbuf[r][wp1] = make_float2(vs1, vq1);
                    const int ys = base + r - PAD;
                    const int ya = base + r + PAD + 1;
                    const float mS = (ys >= 0)    ? 1.f : 0.f;
                    const float mA = (ya < IMG_H) ? 1.f : 0.f;
                    float s0 = sbv[r].x * mS, s1 = sbv[r].y * mS;
                    float a0 = adv[r].x * mA, a1 = adv[r].y * mA;
                    vs0 += a0 - s0; vq0 = fmaf(a0, a0, vq0); vq0 = fmaf(-s0, s0, vq0);
                    vs1 += a1 - s1; vq1 = fmaf(a1, a1, vq1); vq1 = fmaf(-s1, s1, vq1);
                }
                if (p < NPH - 2) {         // prefetch loads for G_{p+2}
                    const int base2 = y0 + GP * (p + 2);
                    #pragma unroll
                    for (int r = 0; r < GP; ++r) {
                        const int ys = base2 + r - PAD;
                        const int ya = base2 + r + PAD + 1;
                        sbv[r] = *(const float2*)(img + (size_t)max(ys, 0) * IMG_W + c0);
                        adv[r] = *(const float2*)(img + (size_t)min(ya, IMG_H - 1) * IMG_W + c0);
                    }
                }
            }
        }
    } else {
        // ================= CONSUMER (waves 0..7) =================
        const int cbase = lane << 4;       // 16 contiguous cols per lane

        // Pad init: slots 0..7, left pads (iv<16) and right pads zero.
        if (t < 256) {
            const int s = t >> 5;          // slot 0..7
            const int k = t & 31;
            float2* vb = &vbuf[s][0];
            if (k < 16) vb[k * LROW] = make_float2(0.f, 0.f);
            else        vb[(k - 16) * LROW + (LROW - 1)] = make_float2(0.f, 0.f);
        }

        for (int p = 0; p < NPH; ++p) {
            LDS_BARRIER();                 // B: G_p published & visible
            const int row = y0 + GP * p + wave;

            // x-row issued first; latency hidden under the LDS warm-up.
            const float* xr = img + (size_t)row * IMG_W + cbase;
            float4 xa = ((const float4*)xr)[0];
            float4 xb = ((const float4*)xr)[1];
            float4 xc = ((const float4*)xr)[2];
            float4 xd = ((const float4*)xr)[3];

            const float2* vr = &vbuf[wave][lane];

            // Warm-up with 2-way ILP split.
            float hsA = 0.f, hqA = 0.f, hsB = 0.f, hqB = 0.f;
            #pragma unroll
            for (int s = 1; s <= 31; s += 2) {
                float2 va = vr[(s & 15) * LROW + (s >> 4)];
                hsA += va.x; hqA += va.y;
                if (s + 1 <= 31) {
                    float2 vb2 = vr[((s + 1) & 15) * LROW + ((s + 1) >> 4)];
                    hsB += vb2.x; hqB += vb2.y;
                }
            }
            float hs = hsA + hsB, hq = hqA + hqB;

            float xs[16] = { xa.x, xa.y, xa.z, xa.w,  xb.x, xb.y, xb.z, xb.w,
                             xc.x, xc.y, xc.z, xc.w,  xd.x, xd.y, xd.z, xd.w };
            float res[16];
            #pragma unroll
            for (int j = 0; j < 16; ++j) {
                if (j > 0) {
                    float2 va  = vr[((j - 1) & 15) * LROW + 2];   // iv=cbase+j+31
                    float2 vsu = vr[(j & 15) * LROW];             // iv=cbase+j
                    hs += va.x - vsu.x;
                    hq += va.y - vsu.y;
                }
                const float mean = hs * inv;
                const float var  = fmaf(-mean, mean, hq * inv);
                const float stdv = sqrtf(fmaxf(var, EPSV));
                const float norm = (xs[j] - mean) *
                                   __builtin_amdgcn_rcpf(stdv + EPSV);
                res[j] = __builtin_amdgcn_rcpf(1.0f + __expf(-0.5f * norm));
            }

            // Proven exact-131MB epilogue: 4 back-to-back float4 stores.
            float* orow = oimg + (size_t)row * IMG_W + cbase;
            ((float4*)orow)[0] = make_float4(res[0],  res[1],  res[2],  res[3]);
            ((float4*)orow)[1] = make_float4(res[4],  res[5],  res[6],  res[7]);
            ((float4*)orow)[2] = make_float4(res[8],  res[9],  res[10], res[11]);
            ((float4*)orow)[3] = make_float4(res[12], res[13], res[14], res[15]);

            LDS_BARRIER();                 // A: release buffer for republish
        }
    }
}

extern "C" void kernel_launch(void* const* d_in, const int* in_sizes, int n_in,
                              void* d_out, int out_size, void* d_ws, size_t ws_size,
                              hipStream_t stream) {
    (void)n_in; (void)out_size; (void)d_ws; (void)ws_size;
    const float* x = (const float*)d_in[0];
    float* out = (float*)d_out;
    const int B = in_sizes[0] / (IMG_H * IMG_W);   // 32
    dim3 grid(B * (IMG_H / SH));                   // 512 blocks, 2 per CU
    lcn_fused_kernel<<<grid, NT, 0, stream>>>(x, out);
}

// Round 16
// 92.243 us; speedup vs baseline: 1.7681x; 1.0502x over previous
//
#include <hip/hip_runtime.h>
#include <math.h>

// LocalContrastNormalization: out = sigmoid(0.5*(x-mu)/(sigma+eps)),
// mu/sigma from 31x31 zero-padded box filter (separable).
// v16 = v10 (best: producer/consumer waves, double-buffered transposed LDS,
// lgkm-only barriers, full-width rows, exact-131MB store epilogue) + ONE
// change: CONSUMER X-PREFETCH. The consumer's x-row has ~16-row reuse
// distance from the producer's read -> evicted from the 4MB L2 -> L3/HBM
// latency sat on the consumer critical path every phase. Now phase p+1's
// x-row loads are issued right after phase p's barrier and consumed a full
// phase later; they stay in flight across the lgkm-only barriers.

#define KSZ    31
#define PAD    15
#define IMG_H  1024
#define IMG_W  1024
#define SH     64                // rows per block
#define GP     4                 // rows per group/phase
#define NPH    (SH / GP)         // 16 phases
#define NT     512
#define LROW   66                // transposed stride in float2 units
#define LBUF   (16 * LROW)       // 1056 float2 per row-slot
#define EPSV   1e-5f

#define LDS_BARRIER() do {                                   \
    asm volatile("s_waitcnt lgkmcnt(0)" ::: "memory");       \
    __builtin_amdgcn_s_barrier();                            \
} while (0)

__global__ __launch_bounds__(NT, 4)
void lcn_fused_kernel(const float* __restrict__ x, float* __restrict__ out) {
    // XCD-aware bijective swizzle (gridDim.x = 512, %8==0).
    const int cpx = gridDim.x >> 3;
    const int bid = (blockIdx.x & 7) * cpx + (blockIdx.x >> 3);

    const int chunk = bid & 15;            // 16 chunks of 64 rows per image
    const int b     = bid >> 4;
    const int y0    = chunk * SH;

    const float* img  = x   + (size_t)b * (IMG_H * IMG_W);
    float*       oimg = out + (size_t)b * (IMG_H * IMG_W);

    __shared__ float2 vbuf[2][GP][LBUF];   // double-buffered, transposed

    const int t    = threadIdx.x;
    const int wave = t >> 6;               // 0..7
    const int lane = t & 63;

    // Pad init: left pads (iv<16) and right pads zero.
    if (t < 256) {
        const int s = t >> 5;              // slot 0..7
        const int k = t & 31;
        float2* vb = &vbuf[s >> 2][s & 3][0];
        if (k < 16) vb[k * LROW] = make_float2(0.f, 0.f);
        else        vb[(k - 16) * LROW + (LROW - 1)] = make_float2(0.f, 0.f);
    }

    const float inv = 1.0f / 961.0f;

    if (wave >= 4) {
        // ================= PRODUCER (waves 4..7) =================
        const int pt = t & 255;            // 0..255
        const int c0 = 4 * pt;             // 4 consecutive cols

        const int iv  = c0 + 16;
        const int wp0 = ((iv    ) & 15) * LROW + ((iv    ) >> 4);
        const int wp1 = ((iv + 1) & 15) * LROW + ((iv + 1) >> 4);
        const int wp2 = ((iv + 2) & 15) * LROW + ((iv + 2) >> 4);
        const int wp3 = ((iv + 3) & 15) * LROW + ((iv + 3) >> 4);

        // Warm-up: W(y0) over rows [y0-15, y0+15] (top never clips).
        float vs0=0,vs1=0,vs2=0,vs3=0, vq0=0,vq1=0,vq2=0,vq3=0;
        for (int y = y0 - PAD; y <= y0 + PAD; ++y) {
            const int yc = max(y, 0);
            float4 v = *(const float4*)(img + (size_t)yc * IMG_W + c0);
            const float m = (y >= 0) ? 1.f : 0.f;
            v.x *= m; v.y *= m; v.z *= m; v.w *= m;
            vs0 += v.x; vq0 = fmaf(v.x, v.x, vq0);
            vs1 += v.y; vq1 = fmaf(v.y, v.y, vq1);
            vs2 += v.z; vq2 = fmaf(v.z, v.z, vq2);
            vs3 += v.w; vq3 = fmaf(v.w, v.w, vq3);
        }

        // Prologue: publish G0 (rows y0..y0+3) into buf0, sliding directly.
        #pragma unroll
        for (int r = 0; r < GP; ++r) {
            vbuf[0][r][wp0] = make_float2(vs0, vq0);
            vbuf[0][r][wp1] = make_float2(vs1, vq1);
            vbuf[0][r][wp2] = make_float2(vs2, vq2);
            vbuf[0][r][wp3] = make_float2(vs3, vq3);
            const int ys  = y0 + r - PAD;
            const int ya  = y0 + r + PAD + 1;      // <= y0+19: never clips
            const int ysc = max(ys, 0);
            float4 vS = *(const float4*)(img + (size_t)ysc * IMG_W + c0);
            float4 vA = *(const float4*)(img + (size_t)ya  * IMG_W + c0);
            const float mS = (ys >= 0) ? 1.f : 0.f;
            float s0 = vS.x*mS, s1 = vS.y*mS, s2 = vS.z*mS, s3 = vS.w*mS;
            vs0 += vA.x - s0; vq0 = fmaf(vA.x, vA.x, vq0); vq0 = fmaf(-s0, s0, vq0);
            vs1 += vA.y - s1; vq1 = fmaf(vA.y, vA.y, vq1); vq1 = fmaf(-s1, s1, vq1);
            vs2 += vA.z - s2; vq2 = fmaf(vA.z, vA.z, vq2); vq2 = fmaf(-s2, s2, vq2);
            vs3 += vA.w - s3; vq3 = fmaf(vA.w, vA.w, vq3); vq3 = fmaf(-s3, s3, vq3);
        }

        // Prefetch slide rows for phase 0's publish (base y0+GP).
        float4 pfS[GP], pfA[GP];
        {
            const int base = y0 + GP;
            #pragma unroll
            for (int r = 0; r < GP; ++r) {
                const int ys = base + r - PAD;
                const int ya = base + r + PAD + 1;
                pfS[r] = *(const float4*)(img + (size_t)max(ys, 0) * IMG_W + c0);
                pfA[r] = *(const float4*)(img + (size_t)min(ya, IMG_H - 1) * IMG_W + c0);
            }
        }

        for (int p = 0; p < NPH; ++p) {
            LDS_BARRIER();
            if (p < NPH - 1) {
                const int base = y0 + GP * (p + 1);
                float2* dst = &vbuf[(p + 1) & 1][0][0];
                #pragma unroll
                for (int r = 0; r < GP; ++r) {
                    float2* d = dst + r * LBUF;
                    d[wp0] = make_float2(vs0, vq0);
                    d[wp1] = make_float2(vs1, vq1);
                    d[wp2] = make_float2(vs2, vq2);
                    d[wp3] = make_float2(vs3, vq3);
                    const int ys = base + r - PAD;
                    const int ya = base + r + PAD + 1;
                    const float mS = (ys >= 0)    ? 1.f : 0.f;
                    const float mA = (ya < IMG_H) ? 1.f : 0.f;
                    float s0 = pfS[r].x*mS, s1 = pfS[r].y*mS,
                          s2 = pfS[r].z*mS, s3 = pfS[r].w*mS;
                    float a0 = pfA[r].x*mA, a1 = pfA[r].y*mA,
                          a2 = pfA[r].z*mA, a3 = pfA[r].w*mA;
                    vs0 += a0 - s0; vq0 = fmaf(a0, a0, vq0); vq0 = fmaf(-s0, s0, vq0);
                    vs1 += a1 - s1; vq1 = fmaf(a1, a1, vq1); vq1 = fmaf(-s1, s1, vq1);
                    vs2 += a2 - s2; vq2 = fmaf(a2, a2, vq2); vq2 = fmaf(-s2, s2, vq2);
                    vs3 += a3 - s3; vq3 = fmaf(a3, a3, vq3); vq3 = fmaf(-s3, s3, vq3);
                }
                if (p < NPH - 2) {        // prefetch for next phase's publish
                    const int base2 = y0 + GP * (p + 2);
                    #pragma unroll
                    for (int r = 0; r < GP; ++r) {
                        const int ys = base2 + r - PAD;
                        const int ya = base2 + r + PAD + 1;
                        pfS[r] = *(const float4*)(img + (size_t)max(ys, 0) * IMG_W + c0);
                        pfA[r] = *(const float4*)(img + (size_t)min(ya, IMG_H - 1) * IMG_W + c0);
                    }
                }
            }
        }
    } else {
        // ================= CONSUMER (waves 0..3) =================
        const int cbase = lane << 4;       // 16 contiguous cols per lane

        // Prefetch phase-0 x-row.
        float4 nxa, nxb, nxc, nxd;
        {
            const float* xr = img + (size_t)(y0 + wave) * IMG_W + cbase;
            nxa = ((const float4*)xr)[0]; nxb = ((const float4*)xr)[1];
            nxc = ((const float4*)xr)[2]; nxd = ((const float4*)xr)[3];
        }

        for (int p = 0; p < NPH; ++p) {
            LDS_BARRIER();
            const int row = y0 + GP * p + wave;

            // Consume prefetched x; issue NEXT phase's x-row immediately so
            // it has the whole compute phase (and barriers) to land.
            float4 xa = nxa, xb = nxb, xc = nxc, xd = nxd;
            if (p < NPH - 1) {
                const float* xr = img + (size_t)(row + GP) * IMG_W + cbase;
                nxa = ((const float4*)xr)[0]; nxb = ((const float4*)xr)[1];
                nxc = ((const float4*)xr)[2]; nxd = ((const float4*)xr)[3];
            }

            const float2* vr = &vbuf[p & 1][wave][lane];

            // Warm-up with 2-way ILP split.
            float hsA = 0.f, hqA = 0.f, hsB = 0.f, hqB = 0.f;
            #pragma unroll
            for (int s = 1; s <= 31; s += 2) {
                float2 va = vr[(s & 15) * LROW + (s >> 4)];
                hsA += va.x; hqA += va.y;
                if (s + 1 <= 31) {
                    float2 vb2 = vr[((s + 1) & 15) * LROW + ((s + 1) >> 4)];
                    hsB += vb2.x; hqB += vb2.y;
                }
            }
            float hs = hsA + hsB, hq = hqA + hqB;

            float xs[16] = { xa.x, xa.y, xa.z, xa.w,  xb.x, xb.y, xb.z, xb.w,
                             xc.x, xc.y, xc.z, xc.w,  xd.x, xd.y, xd.z, xd.w };
            float res[16];
            #pragma unroll
            for (int j = 0; j < 16; ++j) {
                if (j > 0) {
                    float2 va  = vr[((j - 1) & 15) * LROW + 2];   // iv=cbase+j+31
                    float2 vsu = vr[(j & 15) * LROW];             // iv=cbase+j
                    hs += va.x - vsu.x;
                    hq += va.y - vsu.y;
                }
                const float mean = hs * inv;
                const float var  = fmaf(-mean, mean, hq * inv);
                const float stdv = sqrtf(fmaxf(var, EPSV));
                const float norm = (xs[j] - mean) *
                                   __builtin_amdgcn_rcpf(stdv + EPSV);
                res[j] = __builtin_amdgcn_rcpf(1.0f + __expf(-0.5f * norm));
            }

            // Proven exact-131MB epilogue: 4 back-to-back float4 stores.
            float* orow = oimg + (size_t)row * IMG_W + cbase;
            ((float4*)orow)[0] = make_float4(res[0],  res[1],  res[2],  res[3]);
            ((float4*)orow)[1] = make_float4(res[4],  res[5],  res[6],  res[7]);
            ((float4*)orow)[2] = make_float4(res[8],  res[9],  res[10], res[11]);
            ((float4*)orow)[3] = make_float4(res[12], res[13], res[14], res[15]);
        }
    }
}

extern "C" void kernel_launch(void* const* d_in, const int* in_sizes, int n_in,
                              void* d_out, int out_size, void* d_ws, size_t ws_size,
                              hipStream_t stream) {
    (void)n_in; (void)out_size; (void)d_ws; (void)ws_size;
    const float* x = (const float*)d_in[0];
    float* out = (float*)d_out;
    const int B = in_sizes[0] / (IMG_H * IMG_W);   // 32
    dim3 grid(B * (IMG_H / SH));                   // 512 blocks, 2 per CU
    lcn_fused_kernel<<<grid, NT, 0, stream>>>(x, out);
}

// Round 17
// 89.967 us; speedup vs baseline: 1.8129x; 1.0253x over previous
//
#include <hip/hip_runtime.h>
#include <math.h>

// LocalContrastNormalization: out = sigmoid(0.5*(x-mu)/(sigma+eps)),
// mu/sigma from 31x31 zero-padded box filter (separable).
// v17 = v10 (best: producer/consumer waves, double-buffered transposed LDS,
// lgkm-only barriers, full-width rows, exact-131MB store epilogue) with ONE
// change: 8 PRODUCER WAVES (NT=768, 2 cols/thread) instead of 4. v10's
// producers issue their phase loads in one burst then idle -> bursty MLP,
// low average outstanding bytes. Doubling producer waves doubles per-CU
// outstanding loads and smooths issue. Consumers identical to v10.
// 24 waves/CU (2 blocks x 12). LDS unchanged 67.6 KB.

#define KSZ    31
#define PAD    15
#define IMG_H  1024
#define IMG_W  1024
#define SH     64                // rows per block
#define GP     4                 // rows per group/phase
#define NPH    (SH / GP)         // 16 phases
#define NT     768               // waves 0..3 consumers, 4..11 producers
#define LROW   66                // transposed stride in float2 units
#define LBUF   (16 * LROW)       // 1056 float2 per row-slot
#define EPSV   1e-5f

#define LDS_BARRIER() do {                                   \
    asm volatile("s_waitcnt lgkmcnt(0)" ::: "memory");       \
    __builtin_amdgcn_s_barrier();                            \
} while (0)

__global__ __launch_bounds__(NT, 6)
void lcn_fused_kernel(const float* __restrict__ x, float* __restrict__ out) {
    // XCD-aware bijective swizzle (gridDim.x = 512, %8==0).
    const int cpx = gridDim.x >> 3;
    const int bid = (blockIdx.x & 7) * cpx + (blockIdx.x >> 3);

    const int chunk = bid & 15;            // 16 chunks of 64 rows per image
    const int b     = bid >> 4;
    const int y0    = chunk * SH;

    const float* img  = x   + (size_t)b * (IMG_H * IMG_W);
    float*       oimg = out + (size_t)b * (IMG_H * IMG_W);

    __shared__ float2 vbuf[2][GP][LBUF];   // double-buffered, transposed

    const int t    = threadIdx.x;
    const int wave = t >> 6;               // 0..11
    const int lane = t & 63;

    // Pad init (consumer threads): left pads (iv<16) and right pads zero.
    if (t < 256) {
        const int s = t >> 5;              // slot 0..7
        const int k = t & 31;
        float2* vb = &vbuf[s >> 2][s & 3][0];
        if (k < 16) vb[k * LROW] = make_float2(0.f, 0.f);
        else        vb[(k - 16) * LROW + (LROW - 1)] = make_float2(0.f, 0.f);
    }

    const float inv = 1.0f / 961.0f;

    if (wave >= 4) {
        // ================= PRODUCER (waves 4..11) =================
        const int pt = t - 256;            // 0..511
        const int c0 = 2 * pt;             // 2 consecutive cols

        const int iv  = c0 + 16;
        const int wp0 = ((iv    ) & 15) * LROW + ((iv    ) >> 4);
        const int wp1 = ((iv + 1) & 15) * LROW + ((iv + 1) >> 4);

        // Warm-up: W(y0) over rows [y0-15, y0+15] (top never clips: y0<=960).
        float vs0 = 0.f, vq0 = 0.f, vs1 = 0.f, vq1 = 0.f;
        for (int y = y0 - PAD; y <= y0 + PAD; ++y) {
            const int yc = max(y, 0);
            float2 v = *(const float2*)(img + (size_t)yc * IMG_W + c0);
            const float m = (y >= 0) ? 1.f : 0.f;
            v.x *= m; v.y *= m;
            vs0 += v.x; vq0 = fmaf(v.x, v.x, vq0);
            vs1 += v.y; vq1 = fmaf(v.y, v.y, vq1);
        }

        // Prologue: publish G0 (rows y0..y0+3) into buf0, sliding directly.
        #pragma unroll
        for (int r = 0; r < GP; ++r) {
            vbuf[0][r][wp0] = make_float2(vs0, vq0);
            vbuf[0][r][wp1] = make_float2(vs1, vq1);
            const int ys  = y0 + r - PAD;
            const int ya  = y0 + r + PAD + 1;      // <= y0+19: never clips
            const int ysc = max(ys, 0);
            float2 vS = *(const float2*)(img + (size_t)ysc * IMG_W + c0);
            float2 vA = *(const float2*)(img + (size_t)ya  * IMG_W + c0);
            const float mS = (ys >= 0) ? 1.f : 0.f;
            float s0 = vS.x * mS, s1 = vS.y * mS;
            vs0 += vA.x - s0; vq0 = fmaf(vA.x, vA.x, vq0); vq0 = fmaf(-s0, s0, vq0);
            vs1 += vA.y - s1; vq1 = fmaf(vA.y, vA.y, vq1); vq1 = fmaf(-s1, s1, vq1);
        }

        // Prefetch slide rows for phase 0's publish (base y0+GP).
        float2 pfS[GP], pfA[GP];
        {
            const int base = y0 + GP;
            #pragma unroll
            for (int r = 0; r < GP; ++r) {
                const int ys = base + r - PAD;
                const int ya = base + r + PAD + 1;
                pfS[r] = *(const float2*)(img + (size_t)max(ys, 0) * IMG_W + c0);
                pfA[r] = *(const float2*)(img + (size_t)min(ya, IMG_H - 1) * IMG_W + c0);
            }
        }

        for (int p = 0; p < NPH; ++p) {
            LDS_BARRIER();
            if (p < NPH - 1) {
                const int base = y0 + GP * (p + 1);
                float2* dst = &vbuf[(p + 1) & 1][0][0];
                #pragma unroll
                for (int r = 0; r < GP; ++r) {
                    float2* d = dst + r * LBUF;
                    d[wp0] = make_float2(vs0, vq0);
                    d[wp1] = make_float2(vs1, vq1);
                    const int ys = base + r - PAD;
                    const int ya = base + r + PAD + 1;
                    const float mS = (ys >= 0)    ? 1.f : 0.f;
                    const float mA = (ya < IMG_H) ? 1.f : 0.f;
                    float s0 = pfS[r].x * mS, s1 = pfS[r].y * mS;
                    float a0 = pfA[r].x * mA, a1 = pfA[r].y * mA;
                    vs0 += a0 - s0; vq0 = fmaf(a0, a0, vq0); vq0 = fmaf(-s0, s0, vq0);
                    vs1 += a1 - s1; vq1 = fmaf(a1, a1, vq1); vq1 = fmaf(-s1, s1, vq1);
                }
                if (p < NPH - 2) {        // prefetch for next phase's publish
                    const int base2 = y0 + GP * (p + 2);
                    #pragma unroll
                    for (int r = 0; r < GP; ++r) {
                        const int ys = base2 + r - PAD;
                        const int ya = base2 + r + PAD + 1;
                        pfS[r] = *(const float2*)(img + (size_t)max(ys, 0) * IMG_W + c0);
                        pfA[r] = *(const float2*)(img + (size_t)min(ya, IMG_H - 1) * IMG_W + c0);
                    }
                }
            }
        }
    } else {
        // ================= CONSUMER (waves 0..3) =================
        const int cbase = lane << 4;       // 16 contiguous cols per lane

        for (int p = 0; p < NPH; ++p) {
            LDS_BARRIER();
            const int row = y0 + GP * p + wave;

            // x-row issued first; latency hidden under the LDS warm-up.
            const float* xr = img + (size_t)row * IMG_W + cbase;
            float4 xa = ((const float4*)xr)[0];
            float4 xb = ((const float4*)xr)[1];
            float4 xc = ((const float4*)xr)[2];
            float4 xd = ((const float4*)xr)[3];

            const float2* vr = &vbuf[p & 1][wave][lane];

            // Warm-up with 2-way ILP split.
            float hsA = 0.f, hqA = 0.f, hsB = 0.f, hqB = 0.f;
            #pragma unroll
            for (int s = 1; s <= 31; s += 2) {
                float2 va = vr[(s & 15) * LROW + (s >> 4)];
                hsA += va.x; hqA += va.y;
                if (s + 1 <= 31) {
                    float2 vb2 = vr[((s + 1) & 15) * LROW + ((s + 1) >> 4)];
                    hsB += vb2.x; hqB += vb2.y;
                }
            }
            float hs = hsA + hsB, hq = hqA + hqB;

            float xs[16] = { xa.x, xa.y, xa.z, xa.w,  xb.x, xb.y, xb.z, xb.w,
                             xc.x, xc.y, xc.z, xc.w,  xd.x, xd.y, xd.z, xd.w };
            float res[16];
            #pragma unroll
            for (int j = 0; j < 16; ++j) {
                if (j > 0) {
                    float2 va  = vr[((j - 1) & 15) * LROW + 2];   // iv=cbase+j+31
                    float2 vsu = vr[(j & 15) * LROW];             // iv=cbase+j
                    hs += va.x - vsu.x;
                    hq += va.y - vsu.y;
                }
                const float mean = hs * inv;
                const float var  = fmaf(-mean, mean, hq * inv);
                const float stdv = sqrtf(fmaxf(var, EPSV));
                const float norm = (xs[j] - mean) *
                                   __builtin_amdgcn_rcpf(stdv + EPSV);
                res[j] = __builtin_amdgcn_rcpf(1.0f + __expf(-0.5f * norm));
            }

            // Proven exact-131MB epilogue: 4 back-to-back float4 stores.
            float* orow = oimg + (size_t)row * IMG_W + cbase;
            ((float4*)orow)[0] = make_float4(res[0],  res[1],  res[2],  res[3]);
            ((float4*)orow)[1] = make_float4(res[4],  res[5],  res[6],  res[7]);
            ((float4*)orow)[2] = make_float4(res[8],  res[9],  res[10], res[11]);
            ((float4*)orow)[3] = make_float4(res[12], res[13], res[14], res[15]);
        }
    }
}

extern "C" void kernel_launch(void* const* d_in, const int* in_sizes, int n_in,
                              void* d_out, int out_size, void* d_ws, size_t ws_size,
                              hipStream_t stream) {
    (void)n_in; (void)out_size; (void)d_ws; (void)ws_size;
    const float* x = (const float*)d_in[0];
    float* out = (float*)d_out;
    const int B = in_sizes[0] / (IMG_H * IMG_W);   // 32
    dim3 grid(B * (IMG_H / SH));                   // 512 blocks, 2 per CU
    lcn_fused_kernel<<<grid, NT, 0, stream>>>(x, out);
}

// Round 18
// 85.303 us; speedup vs baseline: 1.9120x; 1.0547x over previous
//
#include <hip/hip_runtime.h>
#include <math.h>

// LocalContrastNormalization: out = sigmoid(0.5*(x-mu)/(sigma+eps)),
// mu/sigma from 31x31 zero-padded box filter (separable).
// v18 = v10 VERBATIM (session best: 85.4 us). Producer/consumer wave
// specialization + double-buffered transposed LDS + lgkm-only barriers.
// Axis sweep completed across R11-R17: occupancy (22-79%), barrier
// semantics, traffic reduction (SH=128 / nt-stores / L2 retention),
// consumer dependency chains (prefix scan), x-prefetch, producer MLP —
// all neutral-to-negative. Effective BW pins at ~4.0-4.3 TB/s across all
// structures => practical mixed-stream ceiling; v10 is within ~10% of the
// 320MB/4.2TB/s floor. This is the final kernel.
//
//  - waves 4..7 (producers): per-thread 4-col vertical sliding sums for the
//    full 1024-wide row; publish group G_{p+1} (4 rows) into buf[(p+1)&1]
//    during phase p; slide loads PREFETCHED one full phase ahead and kept
//    in flight across the lgkm-only barriers.
//  - waves 0..3 (consumers): wave w processes row y0+4p+w from buf[p&1]:
//    31-read transposed-LDS warm-up (2-way ILP split) + 16-col register
//    sliding window + pointwise; compute-all-then-4-back-to-back-float4
//    stores (the proven exact-131MB epilogue).
//  - ONE lgkm-only barrier per phase (double buffer removes the WAR wait).
//  - LDS = 2 x 4 x 1056 float2 = 67.6 KB -> 2 blocks/CU; grid 512.

#define KSZ    31
#define PAD    15
#define IMG_H  1024
#define IMG_W  1024
#define SH     64                // rows per block
#define GP     4                 // rows per group/phase
#define NPH    (SH / GP)         // 16 phases
#define NT     512
#define LROW   66                // transposed stride in float2 units
#define LBUF   (16 * LROW)       // 1056 float2 per row-slot
#define EPSV   1e-5f

#define LDS_BARRIER() do {                                   \
    asm volatile("s_waitcnt lgkmcnt(0)" ::: "memory");       \
    __builtin_amdgcn_s_barrier();                            \
} while (0)

__global__ __launch_bounds__(NT, 4)
void lcn_fused_kernel(const float* __restrict__ x, float* __restrict__ out) {
    // XCD-aware bijective swizzle (gridDim.x = 512, %8==0).
    const int cpx = gridDim.x >> 3;
    const int bid = (blockIdx.x & 7) * cpx + (blockIdx.x >> 3);

    const int chunk = bid & 15;            // 16 chunks of 64 rows per image
    const int b     = bid >> 4;
    const int y0    = chunk * SH;

    const float* img  = x   + (size_t)b * (IMG_H * IMG_W);
    float*       oimg = out + (size_t)b * (IMG_H * IMG_W);

    __shared__ float2 vbuf[2][GP][LBUF];   // double-buffered, transposed

    const int t    = threadIdx.x;
    const int wave = t >> 6;               // 0..7
    const int lane = t & 63;

    // Pad init: left pads (iv<16) and right pads zero.
    if (t < 256) {
        const int s = t >> 5;              // slot 0..7
        const int k = t & 31;
        float2* vb = &vbuf[s >> 2][s & 3][0];
        if (k < 16) vb[k * LROW] = make_float2(0.f, 0.f);
        else        vb[(k - 16) * LROW + (LROW - 1)] = make_float2(0.f, 0.f);
    }

    const float inv = 1.0f / 961.0f;

    if (wave >= 4) {
        // ================= PRODUCER (waves 4..7) =================
        const int pt = t & 255;            // 0..255
        const int c0 = 4 * pt;             // 4 consecutive cols

        const int iv  = c0 + 16;
        const int wp0 = ((iv    ) & 15) * LROW + ((iv    ) >> 4);
        const int wp1 = ((iv + 1) & 15) * LROW + ((iv + 1) >> 4);
        const int wp2 = ((iv + 2) & 15) * LROW + ((iv + 2) >> 4);
        const int wp3 = ((iv + 3) & 15) * LROW + ((iv + 3) >> 4);

        // Warm-up: W(y0) over rows [y0-15, y0+15] (top never clips).
        float vs0=0,vs1=0,vs2=0,vs3=0, vq0=0,vq1=0,vq2=0,vq3=0;
        for (int y = y0 - PAD; y <= y0 + PAD; ++y) {
            const int yc = max(y, 0);
            float4 v = *(const float4*)(img + (size_t)yc * IMG_W + c0);
            const float m = (y >= 0) ? 1.f : 0.f;
            v.x *= m; v.y *= m; v.z *= m; v.w *= m;
            vs0 += v.x; vq0 = fmaf(v.x, v.x, vq0);
            vs1 += v.y; vq1 = fmaf(v.y, v.y, vq1);
            vs2 += v.z; vq2 = fmaf(v.z, v.z, vq2);
            vs3 += v.w; vq3 = fmaf(v.w, v.w, vq3);
        }

        // Prologue: publish G0 (rows y0..y0+3) into buf0, sliding directly.
        #pragma unroll
        for (int r = 0; r < GP; ++r) {
            vbuf[0][r][wp0] = make_float2(vs0, vq0);
            vbuf[0][r][wp1] = make_float2(vs1, vq1);
            vbuf[0][r][wp2] = make_float2(vs2, vq2);
            vbuf[0][r][wp3] = make_float2(vs3, vq3);
            const int ys  = y0 + r - PAD;
            const int ya  = y0 + r + PAD + 1;      // <= y0+19: never clips
            const int ysc = max(ys, 0);
            float4 vS = *(const float4*)(img + (size_t)ysc * IMG_W + c0);
            float4 vA = *(const float4*)(img + (size_t)ya  * IMG_W + c0);
            const float mS = (ys >= 0) ? 1.f : 0.f;
            float s0 = vS.x*mS, s1 = vS.y*mS, s2 = vS.z*mS, s3 = vS.w*mS;
            vs0 += vA.x - s0; vq0 = fmaf(vA.x, vA.x, vq0); vq0 = fmaf(-s0, s0, vq0);
            vs1 += vA.y - s1; vq1 = fmaf(vA.y, vA.y, vq1); vq1 = fmaf(-s1, s1, vq1);
            vs2 += vA.z - s2; vq2 = fmaf(vA.z, vA.z, vq2); vq2 = fmaf(-s2, s2, vq2);
            vs3 += vA.w - s3; vq3 = fmaf(vA.w, vA.w, vq3); vq3 = fmaf(-s3, s3, vq3);
        }

        // Prefetch slide rows for phase 0 (publish base y0+GP).
        float4 pfS[GP], pfA[GP];
        {
            const int base = y0 + GP;
            #pragma unroll
            for (int r = 0; r < GP; ++r) {
                const int ys = base + r - PAD;
                const int ya = base + r + PAD + 1;
                pfS[r] = *(const float4*)(img + (size_t)max(ys, 0) * IMG_W + c0);
                pfA[r] = *(const float4*)(img + (size_t)min(ya, IMG_H - 1) * IMG_W + c0);
            }
        }

        for (int p = 0; p < NPH; ++p) {
            LDS_BARRIER();
            if (p < NPH - 1) {
                const int base = y0 + GP * (p + 1);
                float2* dst = &vbuf[(p + 1) & 1][0][0];
                #pragma unroll
                for (int r = 0; r < GP; ++r) {
                    float2* d = dst + r * LBUF;
                    d[wp0] = make_float2(vs0, vq0);
                    d[wp1] = make_float2(vs1, vq1);
                    d[wp2] = make_float2(vs2, vq2);
                    d[wp3] = make_float2(vs3, vq3);
                    const int ys = base + r - PAD;
                    const int ya = base + r + PAD + 1;
                    const float mS = (ys >= 0)    ? 1.f : 0.f;
                    const float mA = (ya < IMG_H) ? 1.f : 0.f;
                    float s0 = pfS[r].x*mS, s1 = pfS[r].y*mS,
                          s2 = pfS[r].z*mS, s3 = pfS[r].w*mS;
                    float a0 = pfA[r].x*mA, a1 = pfA[r].y*mA,
                          a2 = pfA[r].z*mA, a3 = pfA[r].w*mA;
                    vs0 += a0 - s0; vq0 = fmaf(a0, a0, vq0); vq0 = fmaf(-s0, s0, vq0);
                    vs1 += a1 - s1; vq1 = fmaf(a1, a1, vq1); vq1 = fmaf(-s1, s1, vq1);
                    vs2 += a2 - s2; vq2 = fmaf(a2, a2, vq2); vq2 = fmaf(-s2, s2, vq2);
                    vs3 += a3 - s3; vq3 = fmaf(a3, a3, vq3); vq3 = fmaf(-s3, s3, vq3);
                }
                if (p < NPH - 2) {        // prefetch for next phase's publish
                    const int base2 = y0 + GP * (p + 2);
                    #pragma unroll
                    for (int r = 0; r < GP; ++r) {
                        const int ys = base2 + r - PAD;
                        const int ya = base2 + r + PAD + 1;
                        pfS[r] = *(const float4*)(img + (size_t)max(ys, 0) * IMG_W + c0);
                        pfA[r] = *(const float4*)(img + (size_t)min(ya, IMG_H - 1) * IMG_W + c0);
                    }
                }
            }
        }
    } else {
        // ================= CONSUMER (waves 0..3) =================
        const int cbase = lane << 4;       // 16 contiguous cols per lane

        for (int p = 0; p < NPH; ++p) {
            LDS_BARRIER();
            const int row = y0 + GP * p + wave;

            // x-row issued first; latency hidden under the LDS warm-up.
            const float* xr = img + (size_t)row * IMG_W + cbase;
            float4 xa = ((const float4*)xr)[0];
            float4 xb = ((const float4*)xr)[1];
            float4 xc = ((const float4*)xr)[2];
            float4 xd = ((const float4*)xr)[3];

            const float2* vr = &vbuf[p & 1][wave][lane];

            // Warm-up with 2-way ILP split (shortens the serial add chain).
            float hsA = 0.f, hqA = 0.f, hsB = 0.f, hqB = 0.f;
            #pragma unroll
            for (int s = 1; s <= 31; s += 2) {
                float2 va = vr[(s & 15) * LROW + (s >> 4)];
                hsA += va.x; hqA += va.y;
                if (s + 1 <= 31) {
                    float2 vb2 = vr[((s + 1) & 15) * LROW + ((s + 1) >> 4)];
                    hsB += vb2.x; hqB += vb2.y;
                }
            }
            float hs = hsA + hsB, hq = hqA + hqB;

            float xs[16] = { xa.x, xa.y, xa.z, xa.w,  xb.x, xb.y, xb.z, xb.w,
                             xc.x, xc.y, xc.z, xc.w,  xd.x, xd.y, xd.z, xd.w };
            float res[16];
            #pragma unroll
            for (int j = 0; j < 16; ++j) {
                if (j > 0) {
                    float2 va  = vr[((j - 1) & 15) * LROW + 2];   // iv=cbase+j+31
                    float2 vsu = vr[(j & 15) * LROW];             // iv=cbase+j
                    hs += va.x - vsu.x;
                    hq += va.y - vsu.y;
                }
                const float mean = hs * inv;
                const float var  = fmaf(-mean, mean, hq * inv);
                const float stdv = sqrtf(fmaxf(var, EPSV));
                const float norm = (xs[j] - mean) *
                                   __builtin_amdgcn_rcpf(stdv + EPSV);
                res[j] = __builtin_amdgcn_rcpf(1.0f + __expf(-0.5f * norm));
            }

            // Proven exact-131MB epilogue: 4 back-to-back float4 stores.
            float* orow = oimg + (size_t)row * IMG_W + cbase;
            ((float4*)orow)[0] = make_float4(res[0],  res[1],  res[2],  res[3]);
            ((float4*)orow)[1] = make_float4(res[4],  res[5],  res[6],  res[7]);
            ((float4*)orow)[2] = make_float4(res[8],  res[9],  res[10], res[11]);
            ((float4*)orow)[3] = make_float4(res[12], res[13], res[14], res[15]);
        }
    }
}

extern "C" void kernel_launch(void* const* d_in, const int* in_sizes, int n_in,
                              void* d_out, int out_size, void* d_ws, size_t ws_size,
                              hipStream_t stream) {
    (void)n_in; (void)out_size; (void)d_ws; (void)ws_size;
    const float* x = (const float*)d_in[0];
    float* out = (float*)d_out;
    const int B = in_sizes[0] / (IMG_H * IMG_W);   // 32
    dim3 grid(B * (IMG_H / SH));                   // 512 blocks
    lcn_fused_kernel<<<grid, NT, 0, stream>>>(x, out);
}